// Round 13
// baseline (800.611 us; speedup 1.0000x reference)
//
#include <hip/hip_runtime.h>
#include <math.h>

// ============================================================================
// Transformer block, round 13: verbatim resubmission of round-11/12 source
// (two GPU-acquisition timeouts; kernel never executed). QBLK=128 MFMA flash
// attention (2 frag groups per wave, Q direct global->reg, K/V staging
// amortized 2x) + fused-QKV GEMM. B=4, S=2048, D=1024, H=16, dk=64, F=4096.
//
// Workspace (byte offsets, peak ~104 MB):
//   0  WqkvT bf16 [3072][1024] (6 MB)
//   6  WoT (2)   8 W1T (8)   16 W2T (8)
//   24 h bf16 (16)       -> ctx bf16
//   40 qkv bf16 [8192][3072] (48)  -> h2 (16 @40), fc (32 @56) after attn
//   88 vT bf16 (16) [bh][d][s]
//   104 vsum f32 (16 KB), then bqkv f32[3072] (12 KB)
//   d_out: x1 (attn residual f32), then final out (in-place res add, safe).
// ============================================================================

#define NEGV (-1.0e9f)

typedef short bfrag __attribute__((ext_vector_type(8)));   // 8 bf16 (4 VGPR)
typedef float ffrag __attribute__((ext_vector_type(4)));   // mfma f32x4 acc
typedef unsigned short usvec8 __attribute__((ext_vector_type(8)));

__device__ __forceinline__ unsigned short f2bf(float f) {  // RNE f32->bf16
  unsigned u = __float_as_uint(f);
  u += 0x7fffu + ((u >> 16) & 1u);
  return (unsigned short)(u >> 16);
}
__device__ __forceinline__ float bf2f(unsigned short h) {
  return __uint_as_float(((unsigned)h) << 16);
}
__device__ __forceinline__ float gelu_f(float v) {
  return 0.5f * v * (1.0f + erff(v * 0.7071067811865475f));
}
__device__ __forceinline__ void gload16(const void* g, void* l) {
  __builtin_amdgcn_global_load_lds(
      (const __attribute__((address_space(1))) void*)g,
      (__attribute__((address_space(3))) void*)l, 16, 0, 0);
}

// ------------------------------------------- weight transpose+cast fp32->bf16
__global__ __launch_bounds__(256) void transpose_cast(
    const float* __restrict__ src, unsigned short* __restrict__ dst,
    int R, int C) {
  __shared__ float tile[32][33];
  int bx = blockIdx.x, by = blockIdx.y;
  int tx = threadIdx.x & 31, ty = threadIdx.x >> 5;
#pragma unroll
  for (int i = 0; i < 4; ++i)
    tile[ty + i * 8][tx] =
        src[(size_t)(by * 32 + ty + i * 8) * C + bx * 32 + tx];
  __syncthreads();
#pragma unroll
  for (int i = 0; i < 4; ++i)
    dst[(size_t)(bx * 32 + ty + i * 8) * R + by * 32 + tx] =
        f2bf(tile[tx][ty + i * 8]);
}

// --------------------------------------------------- concat bq|bk|bv (f32)
__global__ __launch_bounds__(256) void bias_concat(
    const float* __restrict__ bq, const float* __restrict__ bk,
    const float* __restrict__ bv, float* __restrict__ dst) {
  int i = blockIdx.x * 256 + threadIdx.x;  // 12 blocks x 256 = 3072
  const float* src = (i < 1024) ? bq : (i < 2048 ? bk : bv);
  int off = (i < 1024) ? i : (i < 2048 ? i - 1024 : i - 2048);
  dst[i] = src[off];
}

// ---------------------------------------------------------------- LayerNorm
__global__ __launch_bounds__(256) void ln_bf16(
    const float* __restrict__ X, const float* __restrict__ G,
    const float* __restrict__ Bt, unsigned short* __restrict__ O) {
  int row = blockIdx.x, t = threadIdx.x;
  const float* xr = X + (size_t)row * 1024;
  float4 x4 = *(const float4*)(xr + t * 4);
  float s = x4.x + x4.y + x4.z + x4.w;
#pragma unroll
  for (int off = 1; off < 64; off <<= 1) s += __shfl_xor(s, off);
  __shared__ float p1[4], p2[4];
  int wv = t >> 6, ln = t & 63;
  if (ln == 0) p1[wv] = s;
  __syncthreads();
  float mu = (p1[0] + p1[1] + p1[2] + p1[3]) * (1.0f / 1024.0f);
  float d0 = x4.x - mu, d1 = x4.y - mu, d2 = x4.z - mu, d3 = x4.w - mu;
  float q = d0 * d0 + d1 * d1 + d2 * d2 + d3 * d3;
#pragma unroll
  for (int off = 1; off < 64; off <<= 1) q += __shfl_xor(q, off);
  if (ln == 0) p2[wv] = q;
  __syncthreads();
  float var = (p2[0] + p2[1] + p2[2] + p2[3]) * (1.0f / 1024.0f);
  float rstd = rsqrtf(var + 1e-5f);
  float4 g4 = *(const float4*)(G + t * 4);
  float4 b4 = *(const float4*)(Bt + t * 4);
  ushort4 o4;
  o4.x = f2bf(d0 * rstd * g4.x + b4.x);
  o4.y = f2bf(d1 * rstd * g4.y + b4.y);
  o4.z = f2bf(d2 * rstd * g4.z + b4.z);
  o4.w = f2bf(d3 * rstd * g4.w + b4.w);
  *(ushort4*)(O + (size_t)row * 1024 + t * 4) = o4;
}

// ---------------------------------------------------------------- MFMA GEMM
// (HW-verified r4/r8/r10) C = A(bf16) @ BT^T (+bias)(+gelu)(+res).
template <int DO_BIAS, int DO_RES, int DO_GELU, int OUT_BF16>
__global__ __launch_bounds__(256) void gemm_bf16(
    const unsigned short* __restrict__ A, const unsigned short* __restrict__ BT,
    const float* __restrict__ bias, const float* __restrict__ res,
    void* __restrict__ Cv, int M, int N, int K, int lda, int ldbt, int ldc) {
  __shared__ short Asm[128 * 64];
  __shared__ short Bsm[128 * 64];
  const int t = threadIdx.x;
  const int wv = t >> 6, lane = t & 63;
  const int wm = wv >> 1, wn = wv & 1;
  const int bn0 = blockIdx.x * 128, bm0 = blockIdx.y * 128;
  const int srow = t >> 3, sunit = t & 7;
  ffrag acc[4][4];
#pragma unroll
  for (int i = 0; i < 4; ++i)
#pragma unroll
    for (int j = 0; j < 4; ++j) acc[i][j] = {0.f, 0.f, 0.f, 0.f};

  for (int kk = 0; kk < K; kk += 64) {
#pragma unroll
    for (int i = 0; i < 4; ++i) {
      int row = i * 32 + srow;
      int su = sunit ^ (row & 7);
      gload16(A + (size_t)(bm0 + row) * lda + kk + su * 8,
              Asm + i * 2048 + wv * 512);
    }
#pragma unroll
    for (int i = 0; i < 4; ++i) {
      int row = i * 32 + srow;
      int su = sunit ^ (row & 7);
      gload16(BT + (size_t)(bn0 + row) * ldbt + kk + su * 8,
              Bsm + i * 2048 + wv * 512);
    }
    asm volatile("s_waitcnt vmcnt(0)" ::: "memory");
    __syncthreads();
#pragma unroll
    for (int kh = 0; kh < 2; ++kh) {
      bfrag af[4], bf[4];
#pragma unroll
      for (int mi = 0; mi < 4; ++mi) {
        int row = wm * 64 + mi * 16 + (lane & 15);
        int u = (kh * 4 + (lane >> 4)) ^ (row & 7);
        af[mi] = *(const bfrag*)&Asm[row * 64 + u * 8];
      }
#pragma unroll
      for (int ni = 0; ni < 4; ++ni) {
        int row = wn * 64 + ni * 16 + (lane & 15);
        int u = (kh * 4 + (lane >> 4)) ^ (row & 7);
        bf[ni] = *(const bfrag*)&Bsm[row * 64 + u * 8];
      }
#pragma unroll
      for (int mi = 0; mi < 4; ++mi)
#pragma unroll
        for (int ni = 0; ni < 4; ++ni)
          acc[mi][ni] = __builtin_amdgcn_mfma_f32_16x16x32_bf16(
              af[mi], bf[ni], acc[mi][ni], 0, 0, 0);
    }
    __syncthreads();
  }
  const int crow0 = bm0 + wm * 64 + (lane >> 4) * 4;
  const int ccol0 = bn0 + wn * 64 + (lane & 15);
#pragma unroll
  for (int ni = 0; ni < 4; ++ni) {
    int col = ccol0 + ni * 16;
    float bi = DO_BIAS ? bias[col] : 0.0f;
#pragma unroll
    for (int mi = 0; mi < 4; ++mi) {
#pragma unroll
      for (int r = 0; r < 4; ++r) {
        int row = crow0 + mi * 16 + r;
        float v = acc[mi][ni][r] + bi;
        if (DO_GELU) v = gelu_f(v);
        if (DO_RES) v += res[(size_t)row * ldc + col];
        if (OUT_BF16)
          ((unsigned short*)Cv)[(size_t)row * ldc + col] = f2bf(v);
        else
          ((float*)Cv)[(size_t)row * ldc + col] = v;
      }
    }
  }
}

// ----------------------------------- V [token][ld] slice -> vT[bh][d][s]
__global__ __launch_bounds__(256) void vtrans(
    const unsigned short* __restrict__ V, unsigned short* __restrict__ VT,
    int ld) {
  __shared__ unsigned short tile[64 * 65];  // [d][s], odd stride
  int st = blockIdx.x, bh = blockIdx.y;
  int b = bh >> 4, hh = bh & 15;
  int t = threadIdx.x;
  int s0 = st * 64;
  int sr = t >> 3, u = t & 7;
#pragma unroll
  for (int p = 0; p < 2; ++p) {
    int s = p * 32 + sr;
    usvec8 vv = *(const usvec8*)(V + (size_t)(b * 2048 + s0 + s) * ld +
                                 hh * 64 + u * 8);
#pragma unroll
    for (int j = 0; j < 8; ++j) tile[(u * 8 + j) * 65 + s] = vv[j];
  }
  __syncthreads();
  int dr = t >> 2, c = t & 3;
#pragma unroll
  for (int p = 0; p < 2; ++p) {
    int su = p * 4 + c;
    usvec8 ov;
#pragma unroll
    for (int j = 0; j < 8; ++j) ov[j] = tile[dr * 65 + su * 8 + j];
    *(usvec8*)(VT + (size_t)bh * 64 * 2048 + (size_t)dr * 2048 + s0 + su * 8) =
        ov;
  }
}

// ------------------------------------------------- V column-sum from vT
__global__ __launch_bounds__(256) void vsum_k(
    const unsigned short* __restrict__ VT, float* __restrict__ vsum) {
  int bh = blockIdx.x;
  int t = threadIdx.x;
  int d = t >> 2, c = t & 3;
  const unsigned short* row = VT + (size_t)bh * 131072 + (size_t)d * 2048;
  float acc = 0.0f;
#pragma unroll 4
  for (int i = 0; i < 64; ++i) {
    usvec8 vv = *(const usvec8*)(row + c * 8 + i * 32);
#pragma unroll
    for (int j = 0; j < 8; ++j) acc += bf2f(vv[j]);
  }
  acc += __shfl_xor(acc, 1);
  acc += __shfl_xor(acc, 2);
  if (c == 0) vsum[bh * 64 + d] = acc;
}

// --------------------------------------------------- MFMA flash attention
// grid (S/128, H, B), 4 waves, QBLK=128: each wave owns TWO 16-row fragment
// groups (rows g*64 + wv*16, g in {0,1}) so K-fragments and K/V staging are
// shared across 2x the MFMA work. Q loads straight global->VGPR (exact
// fragment addresses; no LDS). K/V double-buffered with next-tile prefetch.
// Fragment conventions byte-identical to HW-verified r8/r10. Causal mask
// applied per-row only on the last two tiles (kt >= 2*qt); provably inactive
// below the diagonal.
__global__ __launch_bounds__(256) void attn_mfma(
    const unsigned short* __restrict__ QKV, const unsigned short* __restrict__ VT,
    const int* __restrict__ amask, const float* __restrict__ vsum,
    unsigned short* __restrict__ ctx) {
  const int S = 2048, LD = 3072, D = 1024;
  int qt = blockIdx.x, hh = blockIdx.y, b = blockIdx.z;
  int t = threadIdx.x;
  int wv = t >> 6, lane = t & 63;
  int l15 = lane & 15, l4 = lane >> 4;
  __shared__ short Ks[2][64 * 64];
  __shared__ short Vs[2][64 * 64];   // vT tiles: [d][kpos]
  __shared__ short Ps[4][32 * 64];   // per-wave P (32 q-rows x 64 kpos)
  const int srow = t >> 3, sunit = t & 7;

  const unsigned short* kbase = QKV + (size_t)b * S * LD + 1024 + hh * 64;
  const unsigned short* vtb = VT + (size_t)(b * 16 + hh) * 64 * 2048;

  // Q fragments straight from global: group g covers q rows qt*128+g*64+wv*16
  bfrag aq[2][2];
#pragma unroll
  for (int g = 0; g < 2; ++g) {
    const unsigned short* qr =
        QKV + (size_t)(b * S + qt * 128 + g * 64 + wv * 16 + l15) * LD + hh * 64;
#pragma unroll
    for (int kh = 0; kh < 2; ++kh)
      aq[g][kh] = *(const bfrag*)(qr + (kh * 4 + l4) * 8);
  }

  // stage K/V tile 0 into buffer 0
#pragma unroll
  for (int i = 0; i < 2; ++i) {
    int row = i * 32 + srow;
    int su = sunit ^ (row & 7);
    gload16(kbase + (size_t)row * LD + su * 8, &Ks[0][i * 2048 + wv * 512]);
    gload16(vtb + (size_t)row * 2048 + su * 8, &Vs[0][i * 2048 + wv * 512]);
  }
  asm volatile("s_waitcnt vmcnt(0)" ::: "memory");
  __syncthreads();

  ffrag o[2][4];
  float mrun[2][4], lrun[2][4];
#pragma unroll
  for (int g = 0; g < 2; ++g)
#pragma unroll
    for (int r = 0; r < 4; ++r) {
      o[g][r] = {0.f, 0.f, 0.f, 0.f};
      mrun[g][r] = -INFINITY;
      lrun[g][r] = 0.f;
    }
  const int nkt = 2 * qt + 2;
  int cur = 0;

  for (int kt = 0; kt < nkt; ++kt) {
    if (kt) {  // drain prefetched loads for buf[cur]; fence prev readers
      asm volatile("s_waitcnt vmcnt(0)" ::: "memory");
      __syncthreads();
    }
    if (kt + 1 < nkt) {  // prefetch next tile into the other buffer
#pragma unroll
      for (int i = 0; i < 2; ++i) {
        int row = i * 32 + srow;
        int su = sunit ^ (row & 7);
        gload16(kbase + (size_t)((kt + 1) * 64 + row) * LD + su * 8,
                &Ks[cur ^ 1][i * 2048 + wv * 512]);
        gload16(vtb + (size_t)row * 2048 + (kt + 1) * 64 + su * 8,
                &Vs[cur ^ 1][i * 2048 + wv * 512]);
      }
    }
    const short* ksb = Ks[cur];
    const short* vsb = Vs[cur];

    // ---- QK^T for both groups (K fragment loaded once, used twice)
    float sv[2][4][4];  // [g][ni kpos-chunk][reg row]
#pragma unroll
    for (int ni = 0; ni < 4; ++ni) {
      ffrag sf0 = {0.f, 0.f, 0.f, 0.f}, sf1 = {0.f, 0.f, 0.f, 0.f};
#pragma unroll
      for (int kh = 0; kh < 2; ++kh) {
        int row = ni * 16 + l15;
        int u = (kh * 4 + l4) ^ (row & 7);
        bfrag bk = *(const bfrag*)&ksb[row * 64 + u * 8];
        sf0 = __builtin_amdgcn_mfma_f32_16x16x32_bf16(aq[0][kh], bk, sf0, 0, 0, 0);
        sf1 = __builtin_amdgcn_mfma_f32_16x16x32_bf16(aq[1][kh], bk, sf1, 0, 0, 0);
      }
#pragma unroll
      for (int r = 0; r < 4; ++r) {
        sv[0][ni][r] = sf0[r] * 0.125f;
        sv[1][ni][r] = sf1[r] * 0.125f;
      }
    }
    // ---- masks: padding always; causal per-row only near the diagonal
    const bool diag = (kt >= 2 * qt);
#pragma unroll
    for (int ni = 0; ni < 4; ++ni) {
      int kpos = kt * 64 + ni * 16 + l15;
      int mk = amask[b * S + kpos];
#pragma unroll
      for (int g = 0; g < 2; ++g) {
        int q0 = qt * 128 + g * 64 + wv * 16 + l4 * 4;
        if (mk == 0) {
#pragma unroll
          for (int r = 0; r < 4; ++r) sv[g][ni][r] = NEGV;
        } else if (diag) {
#pragma unroll
          for (int r = 0; r < 4; ++r)
            if (kpos > q0 + r) sv[g][ni][r] = NEGV;
        }
      }
    }
    // ---- online softmax (16-lane row groups), fast exp
    float alpha[2][4];
#pragma unroll
    for (int g = 0; g < 2; ++g)
#pragma unroll
      for (int r = 0; r < 4; ++r) {
        float mt = fmaxf(fmaxf(sv[g][0][r], sv[g][1][r]),
                         fmaxf(sv[g][2][r], sv[g][3][r]));
#pragma unroll
        for (int off = 1; off < 16; off <<= 1)
          mt = fmaxf(mt, __shfl_xor(mt, off));
        float mn = fmaxf(mrun[g][r], mt);
        alpha[g][r] = __expf(mrun[g][r] - mn);
        float rs = 0.0f;
#pragma unroll
        for (int ni = 0; ni < 4; ++ni) {
          float pv = __expf(sv[g][ni][r] - mn);
          sv[g][ni][r] = pv;
          rs += pv;
        }
#pragma unroll
        for (int off = 1; off < 16; off <<= 1) rs += __shfl_xor(rs, off);
        lrun[g][r] = lrun[g][r] * alpha[g][r] + rs;
        mrun[g][r] = mn;
      }
    // ---- P -> LDS bf16 (per-wave, swizzled; rows g*16 + l4*4 + r)
#pragma unroll
    for (int g = 0; g < 2; ++g)
#pragma unroll
      for (int ni = 0; ni < 4; ++ni) {
        int cu = ni * 2 + (l15 >> 3);
#pragma unroll
        for (int r = 0; r < 4; ++r) {
          int row = g * 16 + l4 * 4 + r;
          int su = cu ^ (row & 7);
          Ps[wv][row * 64 + su * 8 + (l15 & 7)] = f2bf(sv[g][ni][r]);
        }
      }
    // ---- PV: O[g][16q][64d] += P[g] * vT^T (V fragment loaded once)
#pragma unroll
    for (int g = 0; g < 2; ++g)
#pragma unroll
      for (int ni = 0; ni < 4; ++ni)
#pragma unroll
        for (int r = 0; r < 4; ++r) o[g][ni][r] *= alpha[g][r];
    bfrag pa[2][2];
#pragma unroll
    for (int g = 0; g < 2; ++g)
#pragma unroll
      for (int kh = 0; kh < 2; ++kh) {
        int row = g * 16 + l15;
        int u = (kh * 4 + l4) ^ (row & 7);
        pa[g][kh] = *(const bfrag*)&Ps[wv][row * 64 + u * 8];
      }
#pragma unroll
    for (int ni = 0; ni < 4; ++ni) {
#pragma unroll
      for (int kh = 0; kh < 2; ++kh) {
        int drow = ni * 16 + l15;
        int u = (kh * 4 + l4) ^ (drow & 7);
        bfrag bv = *(const bfrag*)&vsb[drow * 64 + u * 8];
        o[0][ni] = __builtin_amdgcn_mfma_f32_16x16x32_bf16(pa[0][kh], bv, o[0][ni], 0, 0, 0);
        o[1][ni] = __builtin_amdgcn_mfma_f32_16x16x32_bf16(pa[1][kh], bv, o[1][ni], 0, 0, 0);
      }
    }
    cur ^= 1;
  }
  // ---- epilogue: normalize; all-masked rows -> uniform over ALL S keys
#pragma unroll
  for (int g = 0; g < 2; ++g)
#pragma unroll
    for (int r = 0; r < 4; ++r) {
      float inv = 1.0f / lrun[g][r];
      bool allm = (mrun[g][r] <= -1.0e8f);
      int row_g = qt * 128 + g * 64 + wv * 16 + l4 * 4 + r;
#pragma unroll
      for (int ni = 0; ni < 4; ++ni) {
        float val;
        if (allm)
          val = vsum[(b * 16 + hh) * 64 + ni * 16 + l15] * (1.0f / 2048.0f);
        else
          val = o[g][ni][r] * inv;
        ctx[(size_t)(b * S + row_g) * D + hh * 64 + ni * 16 + l15] = f2bf(val);
      }
    }
}

// ============================================================================
extern "C" void kernel_launch(void* const* d_in, const int* in_sizes, int n_in,
                              void* d_out, int out_size, void* d_ws,
                              size_t ws_size, hipStream_t stream) {
  (void)in_sizes; (void)n_in; (void)out_size; (void)ws_size;
  const float* x   = (const float*)d_in[0];
  const int*   am  = (const int*)d_in[1];
  const float* Wq  = (const float*)d_in[2];
  const float* bq  = (const float*)d_in[3];
  const float* Wk  = (const float*)d_in[4];
  const float* bk  = (const float*)d_in[5];
  const float* Wv  = (const float*)d_in[6];
  const float* bv  = (const float*)d_in[7];
  const float* Wo  = (const float*)d_in[8];
  const float* bo  = (const float*)d_in[9];
  const float* W1  = (const float*)d_in[10];
  const float* b1  = (const float*)d_in[11];
  const float* W2  = (const float*)d_in[12];
  const float* b2  = (const float*)d_in[13];
  const float* g1  = (const float*)d_in[14];
  const float* be1 = (const float*)d_in[15];
  const float* g2  = (const float*)d_in[16];
  const float* be2 = (const float*)d_in[17];
  float* out = (float*)d_out;

  unsigned char* w8 = (unsigned char*)d_ws;
  const size_t MB = 1024ull * 1024;
  unsigned short* WqkvT = (unsigned short*)(w8 + 0 * MB);   // [3072][1024]
  unsigned short* WoT   = (unsigned short*)(w8 + 6 * MB);
  unsigned short* W1T   = (unsigned short*)(w8 + 8 * MB);
  unsigned short* W2T   = (unsigned short*)(w8 + 16 * MB);
  unsigned short* h     = (unsigned short*)(w8 + 24 * MB);  // -> ctx
  unsigned short* qkv   = (unsigned short*)(w8 + 40 * MB);  // [8192][3072]
  unsigned short* vT    = (unsigned short*)(w8 + 88 * MB);
  float*          vsm   = (float*)(w8 + 104 * MB);
  float*          bqkv  = (float*)(w8 + 104 * MB + 16 * 1024);
  unsigned short* ctx = h;
  unsigned short* h2  = qkv;                                // reuse after attn
  unsigned short* fc  = (unsigned short*)(w8 + 56 * MB);    // reuse after attn
  float*          x1  = out;

  bias_concat<<<12, 256, 0, stream>>>(bq, bk, bv, bqkv);
  transpose_cast<<<dim3(32, 32), 256, 0, stream>>>(Wq, WqkvT, 1024, 1024);
  transpose_cast<<<dim3(32, 32), 256, 0, stream>>>(Wk, WqkvT + 1024 * 1024, 1024, 1024);
  transpose_cast<<<dim3(32, 32), 256, 0, stream>>>(Wv, WqkvT + 2048 * 1024, 1024, 1024);
  transpose_cast<<<dim3(32, 32), 256, 0, stream>>>(Wo, WoT, 1024, 1024);
  transpose_cast<<<dim3(128, 32), 256, 0, stream>>>(W1, W1T, 1024, 4096);
  transpose_cast<<<dim3(32, 128), 256, 0, stream>>>(W2, W2T, 4096, 1024);

  ln_bf16<<<8192, 256, 0, stream>>>(x, g1, be1, h);
  // fused QKV: [8192][3072]
  gemm_bf16<1, 0, 0, 1><<<dim3(24, 64), 256, 0, stream>>>(
      h, WqkvT, bqkv, nullptr, qkv, 8192, 3072, 1024, 1024, 1024, 3072);
  vtrans<<<dim3(32, 64), 256, 0, stream>>>(qkv + 2048, vT, 3072);
  vsum_k<<<64, 256, 0, stream>>>(vT, vsm);
  attn_mfma<<<dim3(16, 16, 4), 256, 0, stream>>>(qkv, vT, am, vsm, ctx);
  gemm_bf16<1, 1, 0, 0><<<dim3(8, 64), 256, 0, stream>>>(
      ctx, WoT, bo, x, x1, 8192, 1024, 1024, 1024, 1024, 1024);
  ln_bf16<<<8192, 256, 0, stream>>>(x1, g2, be2, h2);
  for (int p = 0; p < 2; ++p) {
    gemm_bf16<1, 0, 1, 1><<<dim3(16, 64), 256, 0, stream>>>(
        h2, W1T + (size_t)p * 2048 * 1024, b1 + p * 2048, nullptr, fc,
        8192, 2048, 1024, 1024, 1024, 2048);
    if (p == 0) {
      gemm_bf16<1, 1, 0, 0><<<dim3(8, 64), 256, 0, stream>>>(
          fc, W2T + p * 2048, b2, x1, out, 8192, 1024, 2048, 2048, 4096, 1024);
    } else {
      gemm_bf16<0, 1, 0, 0><<<dim3(8, 64), 256, 0, stream>>>(
          fc, W2T + p * 2048, nullptr, out, out, 8192, 1024, 2048, 2048, 4096, 1024);
    }
  }
}

// Round 14
// 694.057 us; speedup vs baseline: 1.1535x; 1.1535x over previous
//
#include <hip/hip_runtime.h>
#include <math.h>

// ============================================================================
// Transformer block, round 14: r10 attention (QBLK=64, HW-verified 248us) +
// Q-direct-to-reg (LDS 48->40KB, 4 blocks/CU) + single-pass FFN (chunk=4096).
// B=4, S=2048, D=1024, H=16, dk=64, F=4096.
//
// Workspace (byte offsets, peak 120 MB):
//   0  WqkvT bf16 [3072][1024] (6 MB)
//   6  WoT (2)   8 W1T (8)   16 W2T (8)
//   24 h bf16 (16)       -> ctx bf16
//   40 qkv bf16 [8192][3072] (48)  -> h2 (16 @40), fc (64 @56..120) after attn
//   88 vT bf16 (16) [bh][d][s]     (dead after attn; overwritten by fc)
//   104 vsum f32 (16 KB), then bqkv f32[3072] (12 KB)  (dead after attn)
//   d_out: x1 (attn residual f32), then final out (in-place res add, safe).
// ============================================================================

#define NEGV (-1.0e9f)

typedef short bfrag __attribute__((ext_vector_type(8)));   // 8 bf16 (4 VGPR)
typedef float ffrag __attribute__((ext_vector_type(4)));   // mfma f32x4 acc
typedef unsigned short usvec8 __attribute__((ext_vector_type(8)));

__device__ __forceinline__ unsigned short f2bf(float f) {  // RNE f32->bf16
  unsigned u = __float_as_uint(f);
  u += 0x7fffu + ((u >> 16) & 1u);
  return (unsigned short)(u >> 16);
}
__device__ __forceinline__ float bf2f(unsigned short h) {
  return __uint_as_float(((unsigned)h) << 16);
}
__device__ __forceinline__ float gelu_f(float v) {
  return 0.5f * v * (1.0f + erff(v * 0.7071067811865475f));
}
__device__ __forceinline__ void gload16(const void* g, void* l) {
  __builtin_amdgcn_global_load_lds(
      (const __attribute__((address_space(1))) void*)g,
      (__attribute__((address_space(3))) void*)l, 16, 0, 0);
}

// ------------------------------------------- weight transpose+cast fp32->bf16
__global__ __launch_bounds__(256) void transpose_cast(
    const float* __restrict__ src, unsigned short* __restrict__ dst,
    int R, int C) {
  __shared__ float tile[32][33];
  int bx = blockIdx.x, by = blockIdx.y;
  int tx = threadIdx.x & 31, ty = threadIdx.x >> 5;
#pragma unroll
  for (int i = 0; i < 4; ++i)
    tile[ty + i * 8][tx] =
        src[(size_t)(by * 32 + ty + i * 8) * C + bx * 32 + tx];
  __syncthreads();
#pragma unroll
  for (int i = 0; i < 4; ++i)
    dst[(size_t)(bx * 32 + ty + i * 8) * R + by * 32 + tx] =
        f2bf(tile[tx][ty + i * 8]);
}

// --------------------------------------------------- concat bq|bk|bv (f32)
__global__ __launch_bounds__(256) void bias_concat(
    const float* __restrict__ bq, const float* __restrict__ bk,
    const float* __restrict__ bv, float* __restrict__ dst) {
  int i = blockIdx.x * 256 + threadIdx.x;  // 12 blocks x 256 = 3072
  const float* src = (i < 1024) ? bq : (i < 2048 ? bk : bv);
  int off = (i < 1024) ? i : (i < 2048 ? i - 1024 : i - 2048);
  dst[i] = src[off];
}

// ---------------------------------------------------------------- LayerNorm
__global__ __launch_bounds__(256) void ln_bf16(
    const float* __restrict__ X, const float* __restrict__ G,
    const float* __restrict__ Bt, unsigned short* __restrict__ O) {
  int row = blockIdx.x, t = threadIdx.x;
  const float* xr = X + (size_t)row * 1024;
  float4 x4 = *(const float4*)(xr + t * 4);
  float s = x4.x + x4.y + x4.z + x4.w;
#pragma unroll
  for (int off = 1; off < 64; off <<= 1) s += __shfl_xor(s, off);
  __shared__ float p1[4], p2[4];
  int wv = t >> 6, ln = t & 63;
  if (ln == 0) p1[wv] = s;
  __syncthreads();
  float mu = (p1[0] + p1[1] + p1[2] + p1[3]) * (1.0f / 1024.0f);
  float d0 = x4.x - mu, d1 = x4.y - mu, d2 = x4.z - mu, d3 = x4.w - mu;
  float q = d0 * d0 + d1 * d1 + d2 * d2 + d3 * d3;
#pragma unroll
  for (int off = 1; off < 64; off <<= 1) q += __shfl_xor(q, off);
  if (ln == 0) p2[wv] = q;
  __syncthreads();
  float var = (p2[0] + p2[1] + p2[2] + p2[3]) * (1.0f / 1024.0f);
  float rstd = rsqrtf(var + 1e-5f);
  float4 g4 = *(const float4*)(G + t * 4);
  float4 b4 = *(const float4*)(Bt + t * 4);
  ushort4 o4;
  o4.x = f2bf(d0 * rstd * g4.x + b4.x);
  o4.y = f2bf(d1 * rstd * g4.y + b4.y);
  o4.z = f2bf(d2 * rstd * g4.z + b4.z);
  o4.w = f2bf(d3 * rstd * g4.w + b4.w);
  *(ushort4*)(O + (size_t)row * 1024 + t * 4) = o4;
}

// ---------------------------------------------------------------- MFMA GEMM
// (HW-verified r4/r8/r10) C = A(bf16) @ BT^T (+bias)(+gelu)(+res).
template <int DO_BIAS, int DO_RES, int DO_GELU, int OUT_BF16>
__global__ __launch_bounds__(256) void gemm_bf16(
    const unsigned short* __restrict__ A, const unsigned short* __restrict__ BT,
    const float* __restrict__ bias, const float* __restrict__ res,
    void* __restrict__ Cv, int M, int N, int K, int lda, int ldbt, int ldc) {
  __shared__ short Asm[128 * 64];
  __shared__ short Bsm[128 * 64];
  const int t = threadIdx.x;
  const int wv = t >> 6, lane = t & 63;
  const int wm = wv >> 1, wn = wv & 1;
  const int bn0 = blockIdx.x * 128, bm0 = blockIdx.y * 128;
  const int srow = t >> 3, sunit = t & 7;
  ffrag acc[4][4];
#pragma unroll
  for (int i = 0; i < 4; ++i)
#pragma unroll
    for (int j = 0; j < 4; ++j) acc[i][j] = {0.f, 0.f, 0.f, 0.f};

  for (int kk = 0; kk < K; kk += 64) {
#pragma unroll
    for (int i = 0; i < 4; ++i) {
      int row = i * 32 + srow;
      int su = sunit ^ (row & 7);
      gload16(A + (size_t)(bm0 + row) * lda + kk + su * 8,
              Asm + i * 2048 + wv * 512);
    }
#pragma unroll
    for (int i = 0; i < 4; ++i) {
      int row = i * 32 + srow;
      int su = sunit ^ (row & 7);
      gload16(BT + (size_t)(bn0 + row) * ldbt + kk + su * 8,
              Bsm + i * 2048 + wv * 512);
    }
    asm volatile("s_waitcnt vmcnt(0)" ::: "memory");
    __syncthreads();
#pragma unroll
    for (int kh = 0; kh < 2; ++kh) {
      bfrag af[4], bf[4];
#pragma unroll
      for (int mi = 0; mi < 4; ++mi) {
        int row = wm * 64 + mi * 16 + (lane & 15);
        int u = (kh * 4 + (lane >> 4)) ^ (row & 7);
        af[mi] = *(const bfrag*)&Asm[row * 64 + u * 8];
      }
#pragma unroll
      for (int ni = 0; ni < 4; ++ni) {
        int row = wn * 64 + ni * 16 + (lane & 15);
        int u = (kh * 4 + (lane >> 4)) ^ (row & 7);
        bf[ni] = *(const bfrag*)&Bsm[row * 64 + u * 8];
      }
#pragma unroll
      for (int mi = 0; mi < 4; ++mi)
#pragma unroll
        for (int ni = 0; ni < 4; ++ni)
          acc[mi][ni] = __builtin_amdgcn_mfma_f32_16x16x32_bf16(
              af[mi], bf[ni], acc[mi][ni], 0, 0, 0);
    }
    __syncthreads();
  }
  const int crow0 = bm0 + wm * 64 + (lane >> 4) * 4;
  const int ccol0 = bn0 + wn * 64 + (lane & 15);
#pragma unroll
  for (int ni = 0; ni < 4; ++ni) {
    int col = ccol0 + ni * 16;
    float bi = DO_BIAS ? bias[col] : 0.0f;
#pragma unroll
    for (int mi = 0; mi < 4; ++mi) {
#pragma unroll
      for (int r = 0; r < 4; ++r) {
        int row = crow0 + mi * 16 + r;
        float v = acc[mi][ni][r] + bi;
        if (DO_GELU) v = gelu_f(v);
        if (DO_RES) v += res[(size_t)row * ldc + col];
        if (OUT_BF16)
          ((unsigned short*)Cv)[(size_t)row * ldc + col] = f2bf(v);
        else
          ((float*)Cv)[(size_t)row * ldc + col] = v;
      }
    }
  }
}

// ----------------------------------- V [token][ld] slice -> vT[bh][d][s]
__global__ __launch_bounds__(256) void vtrans(
    const unsigned short* __restrict__ V, unsigned short* __restrict__ VT,
    int ld) {
  __shared__ unsigned short tile[64 * 65];  // [d][s], odd stride
  int st = blockIdx.x, bh = blockIdx.y;
  int b = bh >> 4, hh = bh & 15;
  int t = threadIdx.x;
  int s0 = st * 64;
  int sr = t >> 3, u = t & 7;
#pragma unroll
  for (int p = 0; p < 2; ++p) {
    int s = p * 32 + sr;
    usvec8 vv = *(const usvec8*)(V + (size_t)(b * 2048 + s0 + s) * ld +
                                 hh * 64 + u * 8);
#pragma unroll
    for (int j = 0; j < 8; ++j) tile[(u * 8 + j) * 65 + s] = vv[j];
  }
  __syncthreads();
  int dr = t >> 2, c = t & 3;
#pragma unroll
  for (int p = 0; p < 2; ++p) {
    int su = p * 4 + c;
    usvec8 ov;
#pragma unroll
    for (int j = 0; j < 8; ++j) ov[j] = tile[dr * 65 + su * 8 + j];
    *(usvec8*)(VT + (size_t)bh * 64 * 2048 + (size_t)dr * 2048 + s0 + su * 8) =
        ov;
  }
}

// ------------------------------------------------- V column-sum from vT
__global__ __launch_bounds__(256) void vsum_k(
    const unsigned short* __restrict__ VT, float* __restrict__ vsum) {
  int bh = blockIdx.x;
  int t = threadIdx.x;
  int d = t >> 2, c = t & 3;
  const unsigned short* row = VT + (size_t)bh * 131072 + (size_t)d * 2048;
  float acc = 0.0f;
#pragma unroll 4
  for (int i = 0; i < 64; ++i) {
    usvec8 vv = *(const usvec8*)(row + c * 8 + i * 32);
#pragma unroll
    for (int j = 0; j < 8; ++j) acc += bf2f(vv[j]);
  }
  acc += __shfl_xor(acc, 1);
  acc += __shfl_xor(acc, 2);
  if (c == 0) vsum[bh * 64 + d] = acc;
}

// --------------------------------------------------- MFMA flash attention
// grid (S/64, H, B), 4 waves. r10 structure (HW-verified 248us) with the one
// r13-validated improvement kept: Q loaded straight global->VGPR (exact
// fragment addresses; no Qs buffer) -> LDS 40KB -> 4 blocks/CU. K/V
// double-buffered with next-tile prefetch; one vmcnt+barrier per tile;
// __expf; causal mask only on the diagonal tile.
__global__ __launch_bounds__(256) void attn_mfma(
    const unsigned short* __restrict__ QKV, const unsigned short* __restrict__ VT,
    const int* __restrict__ amask, const float* __restrict__ vsum,
    unsigned short* __restrict__ ctx) {
  const int S = 2048, LD = 3072, D = 1024;
  int qt = blockIdx.x, hh = blockIdx.y, b = blockIdx.z;
  int t = threadIdx.x;
  int wv = t >> 6, lane = t & 63;
  int l15 = lane & 15, l4 = lane >> 4;
  __shared__ short Ks[2][64 * 64];
  __shared__ short Vs[2][64 * 64];   // vT tiles: [d][kpos]
  __shared__ short Ps[4][16 * 64];
  const int srow = t >> 3, sunit = t & 7;

  const unsigned short* kbase = QKV + (size_t)b * S * LD + 1024 + hh * 64;
  const unsigned short* vtb = VT + (size_t)(b * 16 + hh) * 64 * 2048;

  // Q fragments straight from global (wave wv owns q rows qt*64+wv*16..+15)
  bfrag aq[2];
  {
    const unsigned short* qr =
        QKV + (size_t)(b * S + qt * 64 + wv * 16 + l15) * LD + hh * 64;
#pragma unroll
    for (int kh = 0; kh < 2; ++kh)
      aq[kh] = *(const bfrag*)(qr + (kh * 4 + l4) * 8);
  }

  // stage K/V tile 0 into buffer 0
#pragma unroll
  for (int i = 0; i < 2; ++i) {
    int row = i * 32 + srow;
    int su = sunit ^ (row & 7);
    gload16(kbase + (size_t)row * LD + su * 8, &Ks[0][i * 2048 + wv * 512]);
    gload16(vtb + (size_t)row * 2048 + su * 8, &Vs[0][i * 2048 + wv * 512]);
  }
  asm volatile("s_waitcnt vmcnt(0)" ::: "memory");
  __syncthreads();

  ffrag o[4];
#pragma unroll
  for (int ni = 0; ni < 4; ++ni) o[ni] = {0.f, 0.f, 0.f, 0.f};
  float mrun[4] = {-INFINITY, -INFINITY, -INFINITY, -INFINITY};
  float lrun[4] = {0.f, 0.f, 0.f, 0.f};
  const int qrow0 = qt * 64 + wv * 16 + l4 * 4;
  int cur = 0;

  for (int kt = 0; kt <= qt; ++kt) {
    if (kt) {  // drain prefetched loads for buf[cur]; fence prev readers
      asm volatile("s_waitcnt vmcnt(0)" ::: "memory");
      __syncthreads();
    }
    if (kt < qt) {  // prefetch next tile into the other buffer
#pragma unroll
      for (int i = 0; i < 2; ++i) {
        int row = i * 32 + srow;
        int su = sunit ^ (row & 7);
        gload16(kbase + (size_t)((kt + 1) * 64 + row) * LD + su * 8,
                &Ks[cur ^ 1][i * 2048 + wv * 512]);
        gload16(vtb + (size_t)row * 2048 + (kt + 1) * 64 + su * 8,
                &Vs[cur ^ 1][i * 2048 + wv * 512]);
      }
    }
    const short* ksb = Ks[cur];
    const short* vsb = Vs[cur];

    // ---- QK^T: S[16q][64kpos] per wave
    float sv[4][4];  // [ni kpos-chunk][reg row]
#pragma unroll
    for (int ni = 0; ni < 4; ++ni) {
      ffrag sf = {0.f, 0.f, 0.f, 0.f};
#pragma unroll
      for (int kh = 0; kh < 2; ++kh) {
        int row = ni * 16 + l15;
        int u = (kh * 4 + l4) ^ (row & 7);
        bfrag bk = *(const bfrag*)&ksb[row * 64 + u * 8];
        sf = __builtin_amdgcn_mfma_f32_16x16x32_bf16(aq[kh], bk, sf, 0, 0, 0);
      }
#pragma unroll
      for (int r = 0; r < 4; ++r) sv[ni][r] = sf[r] * 0.125f;
    }
    // ---- masks: causal only on the diagonal tile; padding always
    if (kt == qt) {
#pragma unroll
      for (int ni = 0; ni < 4; ++ni) {
        int kpos = kt * 64 + ni * 16 + l15;
        int mk = amask[b * S + kpos];
#pragma unroll
        for (int r = 0; r < 4; ++r)
          if (mk == 0 || kpos > qrow0 + r) sv[ni][r] = NEGV;
      }
    } else {
#pragma unroll
      for (int ni = 0; ni < 4; ++ni) {
        int kpos = kt * 64 + ni * 16 + l15;
        int mk = amask[b * S + kpos];
        if (mk == 0) {
#pragma unroll
          for (int r = 0; r < 4; ++r) sv[ni][r] = NEGV;
        }
      }
    }
    // ---- online softmax (16-lane row groups), fast exp
    float alpha[4];
#pragma unroll
    for (int r = 0; r < 4; ++r) {
      float mt = fmaxf(fmaxf(sv[0][r], sv[1][r]), fmaxf(sv[2][r], sv[3][r]));
#pragma unroll
      for (int off = 1; off < 16; off <<= 1) mt = fmaxf(mt, __shfl_xor(mt, off));
      float mn = fmaxf(mrun[r], mt);
      alpha[r] = __expf(mrun[r] - mn);
      float rs = 0.0f;
#pragma unroll
      for (int ni = 0; ni < 4; ++ni) {
        float pv = __expf(sv[ni][r] - mn);
        sv[ni][r] = pv;
        rs += pv;
      }
#pragma unroll
      for (int off = 1; off < 16; off <<= 1) rs += __shfl_xor(rs, off);
      lrun[r] = lrun[r] * alpha[r] + rs;
      mrun[r] = mn;
    }
    // ---- P -> LDS bf16 (per-wave, swizzled)
#pragma unroll
    for (int ni = 0; ni < 4; ++ni) {
      int cu = ni * 2 + (l15 >> 3);
#pragma unroll
      for (int r = 0; r < 4; ++r) {
        int row = l4 * 4 + r;
        int su = cu ^ (row & 7);
        Ps[wv][row * 64 + su * 8 + (l15 & 7)] = f2bf(sv[ni][r]);
      }
    }
    // ---- PV: O[16q][64d] += P[16q][64kpos] * vT[d][kpos]^T
#pragma unroll
    for (int ni = 0; ni < 4; ++ni)
#pragma unroll
      for (int r = 0; r < 4; ++r) o[ni][r] *= alpha[r];
    bfrag pa[2];
#pragma unroll
    for (int kh = 0; kh < 2; ++kh) {
      int row = l15;
      int u = (kh * 4 + l4) ^ (row & 7);
      pa[kh] = *(const bfrag*)&Ps[wv][row * 64 + u * 8];
    }
#pragma unroll
    for (int ni = 0; ni < 4; ++ni) {
#pragma unroll
      for (int kh = 0; kh < 2; ++kh) {
        int drow = ni * 16 + l15;
        int u = (kh * 4 + l4) ^ (drow & 7);
        bfrag bv = *(const bfrag*)&vsb[drow * 64 + u * 8];
        o[ni] = __builtin_amdgcn_mfma_f32_16x16x32_bf16(pa[kh], bv, o[ni], 0, 0, 0);
      }
    }
    cur ^= 1;
  }
  // ---- epilogue: normalize; all-masked rows -> uniform over ALL S keys
#pragma unroll
  for (int r = 0; r < 4; ++r) {
    float inv = 1.0f / lrun[r];
    bool allm = (mrun[r] <= -1.0e8f);
    int row_g = qrow0 + r;
#pragma unroll
    for (int ni = 0; ni < 4; ++ni) {
      float val;
      if (allm)
        val = vsum[(b * 16 + hh) * 64 + ni * 16 + l15] * (1.0f / 2048.0f);
      else
        val = o[ni][r] * inv;
      ctx[(size_t)(b * S + row_g) * D + hh * 64 + ni * 16 + l15] = f2bf(val);
    }
  }
}

// ============================================================================
extern "C" void kernel_launch(void* const* d_in, const int* in_sizes, int n_in,
                              void* d_out, int out_size, void* d_ws,
                              size_t ws_size, hipStream_t stream) {
  (void)in_sizes; (void)n_in; (void)out_size; (void)ws_size;
  const float* x   = (const float*)d_in[0];
  const int*   am  = (const int*)d_in[1];
  const float* Wq  = (const float*)d_in[2];
  const float* bq  = (const float*)d_in[3];
  const float* Wk  = (const float*)d_in[4];
  const float* bk  = (const float*)d_in[5];
  const float* Wv  = (const float*)d_in[6];
  const float* bv  = (const float*)d_in[7];
  const float* Wo  = (const float*)d_in[8];
  const float* bo  = (const float*)d_in[9];
  const float* W1  = (const float*)d_in[10];
  const float* b1  = (const float*)d_in[11];
  const float* W2  = (const float*)d_in[12];
  const float* b2  = (const float*)d_in[13];
  const float* g1  = (const float*)d_in[14];
  const float* be1 = (const float*)d_in[15];
  const float* g2  = (const float*)d_in[16];
  const float* be2 = (const float*)d_in[17];
  float* out = (float*)d_out;

  unsigned char* w8 = (unsigned char*)d_ws;
  const size_t MB = 1024ull * 1024;
  unsigned short* WqkvT = (unsigned short*)(w8 + 0 * MB);   // [3072][1024]
  unsigned short* WoT   = (unsigned short*)(w8 + 6 * MB);
  unsigned short* W1T   = (unsigned short*)(w8 + 8 * MB);
  unsigned short* W2T   = (unsigned short*)(w8 + 16 * MB);
  unsigned short* h     = (unsigned short*)(w8 + 24 * MB);  // -> ctx
  unsigned short* qkv   = (unsigned short*)(w8 + 40 * MB);  // [8192][3072]
  unsigned short* vT    = (unsigned short*)(w8 + 88 * MB);
  float*          vsm   = (float*)(w8 + 104 * MB);
  float*          bqkv  = (float*)(w8 + 104 * MB + 16 * 1024);
  unsigned short* ctx = h;
  unsigned short* h2  = qkv;                                // reuse after attn
  unsigned short* fc  = (unsigned short*)(w8 + 56 * MB);    // 64MB, after attn
  float*          x1  = out;

  bias_concat<<<12, 256, 0, stream>>>(bq, bk, bv, bqkv);
  transpose_cast<<<dim3(32, 32), 256, 0, stream>>>(Wq, WqkvT, 1024, 1024);
  transpose_cast<<<dim3(32, 32), 256, 0, stream>>>(Wk, WqkvT + 1024 * 1024, 1024, 1024);
  transpose_cast<<<dim3(32, 32), 256, 0, stream>>>(Wv, WqkvT + 2048 * 1024, 1024, 1024);
  transpose_cast<<<dim3(32, 32), 256, 0, stream>>>(Wo, WoT, 1024, 1024);
  transpose_cast<<<dim3(128, 32), 256, 0, stream>>>(W1, W1T, 1024, 4096);
  transpose_cast<<<dim3(32, 128), 256, 0, stream>>>(W2, W2T, 4096, 1024);

  ln_bf16<<<8192, 256, 0, stream>>>(x, g1, be1, h);
  // fused QKV: [8192][3072]
  gemm_bf16<1, 0, 0, 1><<<dim3(24, 64), 256, 0, stream>>>(
      h, WqkvT, bqkv, nullptr, qkv, 8192, 3072, 1024, 1024, 1024, 3072);
  vtrans<<<dim3(32, 64), 256, 0, stream>>>(qkv + 2048, vT, 3072);
  vsum_k<<<64, 256, 0, stream>>>(vT, vsm);
  attn_mfma<<<dim3(32, 16, 4), 256, 0, stream>>>(qkv, vT, am, vsm, ctx);
  gemm_bf16<1, 1, 0, 0><<<dim3(8, 64), 256, 0, stream>>>(
      ctx, WoT, bo, x, x1, 8192, 1024, 1024, 1024, 1024, 1024);
  ln_bf16<<<8192, 256, 0, stream>>>(x1, g2, be2, h2);
  // FFN single pass: fc = gelu(h2 @ W1 + b1)  [8192 x 4096]
  gemm_bf16<1, 0, 1, 1><<<dim3(32, 64), 256, 0, stream>>>(
      h2, W1T, b1, nullptr, fc, 8192, 4096, 1024, 1024, 1024, 4096);
  // out = fc @ W2 + b2 + x1  (K=4096, 64 K-iters)
  gemm_bf16<1, 1, 0, 0><<<dim3(8, 64), 256, 0, stream>>>(
      fc, W2T, b2, x1, out, 8192, 1024, 4096, 4096, 4096, 1024);
}